// Round 12
// baseline (105.888 us; speedup 1.0000x reference)
//
#include <hip/hip_runtime.h>
#include <math.h>

typedef _Float16 half8 __attribute__((ext_vector_type(8)));
typedef float f32x4 __attribute__((ext_vector_type(4)));

// Problem constants
#define BB 32
#define SS 8
#define PP 32
#define SENT 44
#define LL 352          // SS*SENT
#define TT 384          // PP+LL
#define DD 2048
#define H1 512
#define H2 768
#define MM (BB*TT)      // 12288
#define OUT0 (MM*H2)    // 9437184

// async global->LDS, 16B per lane, dest = wave-uniform base + lane*16,
// global source address IS per-lane.
#define GLL16(g, l) __builtin_amdgcn_global_load_lds( \
    (const __attribute__((address_space(1))) void*)(g), \
    (__attribute__((address_space(3))) void*)(l), 16, 0, 0)

// ---------------------------------------------------------------------------
// Gather + concat-add + fp32->f16 (+ fused aux writes):
// A16[m][k], m in [0,12288), k in [0,2048). One block per row, 256 thr x 8.
// Streaming, latency-tolerant. Thread 0 also writes the 3 aux outputs for
// this row (labels / type_ids / att_mask as floats) — saves a dispatch.
// ---------------------------------------------------------------------------
__global__ __launch_bounds__(256) void gather_kernel(
    const float* __restrict__ token_table,
    const int*   __restrict__ topic_ids,
    const int*   __restrict__ input_ids,
    const float* __restrict__ concat_output,
    const int*   __restrict__ tpw_type_ids,
    const int*   __restrict__ type_ids,
    const int*   __restrict__ tpw_att_mask,
    const int*   __restrict__ attention_mask,
    _Float16*    __restrict__ A16,
    float*       __restrict__ out)
{
    const int m = blockIdx.x;
    const int b = m / TT;
    const int t = m % TT;
    const float* src;
    const float* addp = nullptr;
    int tok;
    if (t < PP) {
        tok = topic_ids[b * PP + t];
        src = token_table + (size_t)tok * DD;
    } else {
        int u = t - PP;
        tok = input_ids[b * LL + u];
        src = token_table + (size_t)tok * DD;
        addp = concat_output + ((size_t)b * SS + (u / SENT)) * DD;
    }
    if (threadIdx.x == 0) {
        int ty, mk;
        if (t < PP) {
            ty = tpw_type_ids[b * PP + t];
            mk = tpw_att_mask[b * PP + t];
        } else {
            int u = t - PP;
            ty = type_ids[b * LL + u];
            mk = attention_mask[b * LL + u];
        }
        out[OUT0 + m]          = (float)tok;
        out[OUT0 + MM + m]     = (float)ty;
        out[OUT0 + 2 * MM + m] = (float)mk;
    }
    _Float16* dst = A16 + (size_t)m * DD;
    const int base = threadIdx.x * 8;
    float4 v0 = *(const float4*)(src + base);
    float4 v1 = *(const float4*)(src + base + 4);
    if (addp) {
        float4 c0 = *(const float4*)(addp + base);
        float4 c1 = *(const float4*)(addp + base + 4);
        v0.x += c0.x; v0.y += c0.y; v0.z += c0.z; v0.w += c0.w;
        v1.x += c1.x; v1.y += c1.y; v1.z += c1.z; v1.w += c1.w;
    }
    half8 h;
    h[0] = (_Float16)v0.x; h[1] = (_Float16)v0.y; h[2] = (_Float16)v0.z; h[3] = (_Float16)v0.w;
    h[4] = (_Float16)v1.x; h[5] = (_Float16)v1.y; h[6] = (_Float16)v1.z; h[7] = (_Float16)v1.w;
    *(half8*)(dst + base) = h;
}

// ---------------------------------------------------------------------------
// Transpose + fp32->fp16 convert:  dst[C][R] = (f16) src[R][C]
// ---------------------------------------------------------------------------
__global__ __launch_bounds__(256) void transpose_f16_kernel(
    const float* __restrict__ src, _Float16* __restrict__ dst, int R, int C)
{
    __shared__ float tile[32][33];
    int c0 = blockIdx.x * 32;
    int r0 = blockIdx.y * 32;
    int tx = threadIdx.x & 31;
    int ty = threadIdx.x >> 5;   // 0..7
    #pragma unroll
    for (int i = 0; i < 4; ++i)
        tile[ty + i*8][tx] = src[(size_t)(r0 + ty + i*8) * C + c0 + tx];
    __syncthreads();
    #pragma unroll
    for (int i = 0; i < 4; ++i)
        dst[(size_t)(c0 + ty + i*8) * R + r0 + tx] = (_Float16)tile[tx][ty + i*8];
}

// ---------------------------------------------------------------------------
// GEMM1: H = tanh( A16 @ W1 + b1 ).  A16 f16 [12288][2048], W1T f16
// [512][2048], H f16 [12288][512].
// MAX-OCCUPANCY (R11-proven): tile 64x64, BK=64, 256 thr = 4 waves, wave =
// 32x32 (2x2 frags). LDS 32KB -> 5 blocks/CU (20 waves/CU): per-step vmcnt
// drains of different blocks overlap (m114 TLP). All-GLL16, both-sides XOR
// swizzle. Grid 1536, XCD-chunked (8 bn of a bm on one XCD).
// ---------------------------------------------------------------------------
__global__ __launch_bounds__(256) void gemm1_kernel(
    const _Float16* __restrict__ A16,
    const _Float16* __restrict__ W1T,
    const float*    __restrict__ b1,
    _Float16*       __restrict__ Hout)
{
    const int tid  = threadIdx.x;
    const int wid  = tid >> 6;
    const int lane = tid & 63;

    // 1536 blocks, 192 per XCD (bijective); 8 bn of a bm logical-adjacent.
    const int logical = ((blockIdx.x & 7) * 192) + (blockIdx.x >> 3);
    const int bm = logical >> 3;     // 0..191
    const int bn = logical & 7;      // 0..7

    __shared__ _Float16 As[2][64 * 64];     // 8KB per buf
    __shared__ _Float16 Bs[2][64 * 64];     // 8KB per buf

    const int rl = lane >> 3;            // 0..7 row within 8-row chunk
    const int cg = lane & 7;             // 16B granule within 128B row
    const _Float16* asrc = A16 + (size_t)(bm * 64 + wid * 16 + rl) * DD
                               + ((cg ^ rl) << 3);
    const _Float16* bsrc = W1T + (size_t)(bn * 64 + wid * 16 + rl) * DD
                               + ((cg ^ rl) << 3);

    #define G1_ISSUE(buf, k0) {                                            \
        _Pragma("unroll")                                                  \
        for (int q = 0; q < 2; ++q) {                                      \
            GLL16(asrc + (size_t)q * 8 * DD + (k0),                        \
                  &As[buf][(wid * 16 + q * 8) * 64]);                      \
            GLL16(bsrc + (size_t)q * 8 * DD + (k0),                        \
                  &Bs[buf][(wid * 16 + q * 8) * 64]);                      \
        }                                                                  \
    }

    const int wrow = (wid >> 1) * 32;
    const int wcol = (wid & 1) * 32;
    const int fr   = lane & 15;
    const int fg   = lane >> 4;

    f32x4 acc[2][2] = {};

    G1_ISSUE(0, 0);

    const int NT = DD / 64;   // 32
    for (int t = 0; t < NT; ++t) {
        __syncthreads();                     // drains vmcnt: buf[t&1] ready
        if (t + 1 < NT) G1_ISSUE((t + 1) & 1, (t + 1) * 64);
        const int cb = t & 1;
        #pragma unroll
        for (int kk = 0; kk < 2; ++kk) {
            half8 af[2], bf[2];
            #pragma unroll
            for (int i = 0; i < 2; ++i) {
                int row = wrow + i * 16 + fr;
                af[i] = *(const half8*)&As[cb][
                    (row * 64 + kk * 32 + fg * 8) ^ ((row & 7) << 3)];
            }
            #pragma unroll
            for (int j = 0; j < 2; ++j) {
                int row = wcol + j * 16 + fr;
                bf[j] = *(const half8*)&Bs[cb][
                    (row * 64 + kk * 32 + fg * 8) ^ ((row & 7) << 3)];
            }
            #pragma unroll
            for (int i = 0; i < 2; ++i)
                #pragma unroll
                for (int j = 0; j < 2; ++j)
                    acc[i][j] = __builtin_amdgcn_mfma_f32_16x16x32_f16(
                        af[i], bf[j], acc[i][j], 0, 0, 0);
        }
    }

    #pragma unroll
    for (int i = 0; i < 2; ++i) {
        #pragma unroll
        for (int j = 0; j < 2; ++j) {
            int col = bn * 64 + wcol + j * 16 + fr;
            float bias = b1[col];
            #pragma unroll
            for (int r = 0; r < 4; ++r) {
                int row = bm * 64 + wrow + i * 16 + fg * 4 + r;
                Hout[(size_t)row * H1 + col] = (_Float16)tanhf(acc[i][j][r] + bias);
            }
        }
    }
    #undef G1_ISSUE
}

// ---------------------------------------------------------------------------
// GEMM2: out = H @ W2 + b2.  H f16 [12288][512], W2T f16 [768][512],
// out f32 [12288][768].
// MAX-OCCUPANCY mirror of gemm1: tile 64x64, BK=64, LDS 32KB -> 5 blocks/CU.
// Grid 2304 = 192 bm x 12 bn, XCD-chunked (12 bn of a bm on one XCD -> H
// panel L2-reused; W2T 0.75MB L2-resident). NT=8.
// ---------------------------------------------------------------------------
__global__ __launch_bounds__(256) void gemm2_kernel(
    const _Float16* __restrict__ Hin,
    const _Float16* __restrict__ W2T,
    const float*    __restrict__ b2,
    float*          __restrict__ out)
{
    const int tid  = threadIdx.x;
    const int wid  = tid >> 6;
    const int lane = tid & 63;

    // 2304 blocks, 288 per XCD (bijective)
    const int logical = ((blockIdx.x & 7) * 288) + (blockIdx.x >> 3);
    const int bm = logical / 12;     // 0..191
    const int bn = logical % 12;     // 0..11

    __shared__ _Float16 As[2][64 * 64];     // 8KB per buf
    __shared__ _Float16 Bs[2][64 * 64];

    const int rl = lane >> 3;
    const int cg = lane & 7;
    const _Float16* asrc = Hin + (size_t)(bm * 64 + wid * 16 + rl) * H1
                               + ((cg ^ rl) << 3);
    const _Float16* bsrc = W2T + (size_t)(bn * 64 + wid * 16 + rl) * H1
                               + ((cg ^ rl) << 3);

    #define G2_ISSUE(buf, k0) {                                            \
        _Pragma("unroll")                                                  \
        for (int q = 0; q < 2; ++q) {                                      \
            GLL16(asrc + (size_t)q * 8 * H1 + (k0),                        \
                  &As[buf][(wid * 16 + q * 8) * 64]);                      \
            GLL16(bsrc + (size_t)q * 8 * H1 + (k0),                        \
                  &Bs[buf][(wid * 16 + q * 8) * 64]);                      \
        }                                                                  \
    }

    const int wrow = (wid >> 1) * 32;
    const int wcol = (wid & 1) * 32;
    const int fr   = lane & 15;
    const int fg   = lane >> 4;

    f32x4 acc[2][2] = {};

    G2_ISSUE(0, 0);

    const int NT = H1 / 64;   // 8
    for (int t = 0; t < NT; ++t) {
        __syncthreads();
        if (t + 1 < NT) G2_ISSUE((t + 1) & 1, (t + 1) * 64);
        const int cb = t & 1;
        #pragma unroll
        for (int kk = 0; kk < 2; ++kk) {
            half8 af[2], bf[2];
            #pragma unroll
            for (int i = 0; i < 2; ++i) {
                int row = wrow + i * 16 + fr;
                af[i] = *(const half8*)&As[cb][
                    (row * 64 + kk * 32 + fg * 8) ^ ((row & 7) << 3)];
            }
            #pragma unroll
            for (int j = 0; j < 2; ++j) {
                int row = wcol + j * 16 + fr;
                bf[j] = *(const half8*)&Bs[cb][
                    (row * 64 + kk * 32 + fg * 8) ^ ((row & 7) << 3)];
            }
            #pragma unroll
            for (int i = 0; i < 2; ++i)
                #pragma unroll
                for (int j = 0; j < 2; ++j)
                    acc[i][j] = __builtin_amdgcn_mfma_f32_16x16x32_f16(
                        af[i], bf[j], acc[i][j], 0, 0, 0);
        }
    }

    #pragma unroll
    for (int i = 0; i < 2; ++i) {
        #pragma unroll
        for (int j = 0; j < 2; ++j) {
            int col = bn * 64 + wcol + j * 16 + fr;
            float bias = b2[col];
            #pragma unroll
            for (int r = 0; r < 4; ++r) {
                int row = bm * 64 + wrow + i * 16 + fg * 4 + r;
                out[(size_t)row * H2 + col] = acc[i][j][r] + bias;
            }
        }
    }
    #undef G2_ISSUE
}

extern "C" void kernel_launch(void* const* d_in, const int* in_sizes, int n_in,
                              void* d_out, int out_size, void* d_ws, size_t ws_size,
                              hipStream_t stream) {
    const float* concat_output  = (const float*)d_in[0];
    const int*   input_ids      = (const int*)d_in[1];
    const int*   topic_ids      = (const int*)d_in[2];
    const int*   tpw_att_mask   = (const int*)d_in[3];
    const int*   tpw_type_ids   = (const int*)d_in[4];
    const int*   attention_mask = (const int*)d_in[5];
    const int*   type_ids       = (const int*)d_in[6];
    const float* token_table    = (const float*)d_in[7];
    const float* W1             = (const float*)d_in[8];
    const float* b1             = (const float*)d_in[9];
    const float* W2             = (const float*)d_in[10];
    const float* b2             = (const float*)d_in[11];
    float* out = (float*)d_out;

    _Float16* w1t = (_Float16*)d_ws;            // [512][2048]   2.0 MB
    _Float16* w2t = w1t + (size_t)H1 * DD;      // [768][512]    0.75 MB
    _Float16* Hws = w2t + (size_t)H2 * H1;      // [12288][512]  12.6 MB
    _Float16* A16 = Hws + (size_t)MM * H1;      // [12288][2048] 50.3 MB

    transpose_f16_kernel<<<dim3(H1 / 32, DD / 32), 256, 0, stream>>>(W1, w1t, DD, H1);
    transpose_f16_kernel<<<dim3(H2 / 32, H1 / 32), 256, 0, stream>>>(W2, w2t, H1, H2);
    gather_kernel<<<MM, 256, 0, stream>>>(
        token_table, topic_ids, input_ids, concat_output,
        tpw_type_ids, type_ids, tpw_att_mask, attention_mask, A16, out);

    gemm1_kernel<<<(MM / 64) * (H1 / 64), 256, 0, stream>>>(A16, w1t, b1, Hws);
    gemm2_kernel<<<(MM / 64) * (H2 / 64), 256, 0, stream>>>(Hws, w2t, b2, out);
}

// Round 13
// 103.466 us; speedup vs baseline: 1.0234x; 1.0234x over previous
//
#include <hip/hip_runtime.h>
#include <math.h>

typedef _Float16 half8 __attribute__((ext_vector_type(8)));
typedef float f32x4 __attribute__((ext_vector_type(4)));

// Problem constants
#define BB 32
#define SS 8
#define PP 32
#define SENT 44
#define LL 352          // SS*SENT
#define TT 384          // PP+LL
#define DD 2048
#define H1 512
#define H2 768
#define MM (BB*TT)      // 12288
#define OUT0 (MM*H2)    // 9437184

// async global->LDS, 16B per lane, dest = wave-uniform base + lane*16,
// global source address IS per-lane.
#define GLL16(g, l) __builtin_amdgcn_global_load_lds( \
    (const __attribute__((address_space(1))) void*)(g), \
    (__attribute__((address_space(3))) void*)(l), 16, 0, 0)

// ---------------------------------------------------------------------------
// Gather + concat-add + fp32->f16 (+ fused aux writes):
// A16[m][k], m in [0,12288), k in [0,2048). One block per row, 256 thr x 8.
// Streaming, latency-tolerant. Thread 0 also writes the 3 aux outputs.
// ---------------------------------------------------------------------------
__global__ __launch_bounds__(256) void gather_kernel(
    const float* __restrict__ token_table,
    const int*   __restrict__ topic_ids,
    const int*   __restrict__ input_ids,
    const float* __restrict__ concat_output,
    const int*   __restrict__ tpw_type_ids,
    const int*   __restrict__ type_ids,
    const int*   __restrict__ tpw_att_mask,
    const int*   __restrict__ attention_mask,
    _Float16*    __restrict__ A16,
    float*       __restrict__ out)
{
    const int m = blockIdx.x;
    const int b = m / TT;
    const int t = m % TT;
    const float* src;
    const float* addp = nullptr;
    int tok;
    if (t < PP) {
        tok = topic_ids[b * PP + t];
        src = token_table + (size_t)tok * DD;
    } else {
        int u = t - PP;
        tok = input_ids[b * LL + u];
        src = token_table + (size_t)tok * DD;
        addp = concat_output + ((size_t)b * SS + (u / SENT)) * DD;
    }
    if (threadIdx.x == 0) {
        int ty, mk;
        if (t < PP) {
            ty = tpw_type_ids[b * PP + t];
            mk = tpw_att_mask[b * PP + t];
        } else {
            int u = t - PP;
            ty = type_ids[b * LL + u];
            mk = attention_mask[b * LL + u];
        }
        out[OUT0 + m]          = (float)tok;
        out[OUT0 + MM + m]     = (float)ty;
        out[OUT0 + 2 * MM + m] = (float)mk;
    }
    _Float16* dst = A16 + (size_t)m * DD;
    const int base = threadIdx.x * 8;
    float4 v0 = *(const float4*)(src + base);
    float4 v1 = *(const float4*)(src + base + 4);
    if (addp) {
        float4 c0 = *(const float4*)(addp + base);
        float4 c1 = *(const float4*)(addp + base + 4);
        v0.x += c0.x; v0.y += c0.y; v0.z += c0.z; v0.w += c0.w;
        v1.x += c1.x; v1.y += c1.y; v1.z += c1.z; v1.w += c1.w;
    }
    half8 h;
    h[0] = (_Float16)v0.x; h[1] = (_Float16)v0.y; h[2] = (_Float16)v0.z; h[3] = (_Float16)v0.w;
    h[4] = (_Float16)v1.x; h[5] = (_Float16)v1.y; h[6] = (_Float16)v1.z; h[7] = (_Float16)v1.w;
    *(half8*)(dst + base) = h;
}

// ---------------------------------------------------------------------------
// Transpose + fp32->fp16 convert:  dst[C][R] = (f16) src[R][C]
// ---------------------------------------------------------------------------
__global__ __launch_bounds__(256) void transpose_f16_kernel(
    const float* __restrict__ src, _Float16* __restrict__ dst, int R, int C)
{
    __shared__ float tile[32][33];
    int c0 = blockIdx.x * 32;
    int r0 = blockIdx.y * 32;
    int tx = threadIdx.x & 31;
    int ty = threadIdx.x >> 5;   // 0..7
    #pragma unroll
    for (int i = 0; i < 4; ++i)
        tile[ty + i*8][tx] = src[(size_t)(r0 + ty + i*8) * C + c0 + tx];
    __syncthreads();
    #pragma unroll
    for (int i = 0; i < 4; ++i)
        dst[(size_t)(c0 + ty + i*8) * R + r0 + tx] = (_Float16)tile[tx][ty + i*8];
}

// ---------------------------------------------------------------------------
// GEMM1: H = tanh( A16 @ W1 + b1 ).  A16 f16 [12288][2048], W1T f16
// [512][2048], H f16 [12288][512].
// MAX-TLP variant: tile 64x64, BK=32, 256 thr = 4 waves, wave = 32x32
// (2x2 frags of 16x16x32). LDS = 16KB -> grid 1536 is 6 blocks/CU FULLY
// CO-RESIDENT (24 waves/CU). With 64B rows (BK=32) each wave's frag read
// tiles a CONTIGUOUS 1KB block (16 rows x 4 granules, bijective) ->
// bank-conflict-free with LINEAR LDS, no swizzle. All-GLL16 staging
// (1 A + 1 B issue per wave per step). XCD-chunked grid.
// ---------------------------------------------------------------------------
__global__ __launch_bounds__(256) void gemm1_kernel(
    const _Float16* __restrict__ A16,
    const _Float16* __restrict__ W1T,
    const float*    __restrict__ b1,
    _Float16*       __restrict__ Hout)
{
    const int tid  = threadIdx.x;
    const int wid  = tid >> 6;
    const int lane = tid & 63;

    // 1536 blocks, 192 per XCD (bijective); 8 bn of a bm logical-adjacent.
    const int logical = ((blockIdx.x & 7) * 192) + (blockIdx.x >> 3);
    const int bm = logical >> 3;     // 0..191
    const int bn = logical & 7;      // 0..7

    __shared__ _Float16 As[2][64 * 32];     // 4KB per buf
    __shared__ _Float16 Bs[2][64 * 32];     // 4KB per buf

    // staging: each wave 1 GLL16 per operand = 16 rows x 64B (1KB), linear
    const int rl = lane >> 2;            // 0..15 row within 16-row chunk
    const int cg = lane & 3;             // 16B granule within 64B row
    const _Float16* asrc = A16 + (size_t)(bm * 64 + wid * 16 + rl) * DD
                               + (cg << 3);
    const _Float16* bsrc = W1T + (size_t)(bn * 64 + wid * 16 + rl) * DD
                               + (cg << 3);

    #define G1_ISSUE(buf, k0) {                                            \
        GLL16(asrc + (k0), &As[buf][(wid * 16) * 32]);                     \
        GLL16(bsrc + (k0), &Bs[buf][(wid * 16) * 32]);                     \
    }

    // compute: wave -> 32 rows x 32 cols (2x2 frags of 16x16x32)
    const int wrow = (wid >> 1) * 32;
    const int wcol = (wid & 1) * 32;
    const int fr   = lane & 15;
    const int fg   = lane >> 4;          // 0..3 -> k-granule (8 halfs)

    f32x4 acc[2][2] = {};

    G1_ISSUE(0, 0);

    const int NT = DD / 32;   // 64
    for (int t = 0; t < NT; ++t) {
        __syncthreads();                     // drains vmcnt: buf[t&1] ready
        if (t + 1 < NT) G1_ISSUE((t + 1) & 1, (t + 1) * 32);
        const int cb = t & 1;
        half8 af[2], bf[2];
        #pragma unroll
        for (int i = 0; i < 2; ++i)
            af[i] = *(const half8*)&As[cb][(wrow + i * 16 + fr) * 32 + fg * 8];
        #pragma unroll
        for (int j = 0; j < 2; ++j)
            bf[j] = *(const half8*)&Bs[cb][(wcol + j * 16 + fr) * 32 + fg * 8];
        #pragma unroll
        for (int i = 0; i < 2; ++i)
            #pragma unroll
            for (int j = 0; j < 2; ++j)
                acc[i][j] = __builtin_amdgcn_mfma_f32_16x16x32_f16(
                    af[i], bf[j], acc[i][j], 0, 0, 0);
    }

    // epilogue: bias + tanh -> f16 H
    #pragma unroll
    for (int i = 0; i < 2; ++i) {
        #pragma unroll
        for (int j = 0; j < 2; ++j) {
            int col = bn * 64 + wcol + j * 16 + fr;
            float bias = b1[col];
            #pragma unroll
            for (int r = 0; r < 4; ++r) {
                int row = bm * 64 + wrow + i * 16 + fg * 4 + r;
                Hout[(size_t)row * H1 + col] = (_Float16)tanhf(acc[i][j][r] + bias);
            }
        }
    }
    #undef G1_ISSUE
}

// ---------------------------------------------------------------------------
// GEMM2: out = H @ W2 + b2.  Tile 96x192, BK=64, grid 512 = exactly 2
// blocks/CU (LDS 72KB). Wave = 48x96 (3x6 frags). All-GLL16, both-sides
// swizzle. (R11-proven config — the 64x64 mirror in R12 regressed, traffic-
// bound not latency-bound at 9.7 GF.)
// ---------------------------------------------------------------------------
__global__ __launch_bounds__(256) void gemm2_kernel(
    const _Float16* __restrict__ Hin,
    const _Float16* __restrict__ W2T,
    const float*    __restrict__ b2,
    float*          __restrict__ out)
{
    const int tid  = threadIdx.x;
    const int wid  = tid >> 6;
    const int lane = tid & 63;

    // 512 blocks, 64 per XCD
    const int logical = ((blockIdx.x & 7) * 64) + (blockIdx.x >> 3);
    const int bm = logical >> 2;     // 0..127
    const int bn = logical & 3;      // 0..3

    __shared__ _Float16 As[2][96 * 64];    // 12KB per buf
    __shared__ _Float16 Bs[2][192 * 64];   // 24KB per buf

    const int rl = lane >> 3;
    const int cg = lane & 7;
    const _Float16* asrc = Hin + (size_t)(bm * 96 + wid * 24 + rl) * H1
                               + ((cg ^ rl) << 3);
    const _Float16* bsrc = W2T + (size_t)(bn * 192 + wid * 48 + rl) * H1
                               + ((cg ^ rl) << 3);

    #define G2_ISSUE(buf, k0) {                                           \
        _Pragma("unroll")                                                 \
        for (int q = 0; q < 3; ++q)                                       \
            GLL16(asrc + (size_t)q * 8 * H1 + (k0),                       \
                  &As[buf][(wid * 3 + q) * 512]);                         \
        _Pragma("unroll")                                                 \
        for (int q = 0; q < 6; ++q)                                       \
            GLL16(bsrc + (size_t)q * 8 * H1 + (k0),                       \
                  &Bs[buf][(wid * 6 + q) * 512]);                         \
    }

    const int wrow = (wid >> 1) * 48;
    const int wcol = (wid & 1) * 96;
    const int fr   = lane & 15;
    const int fg   = lane >> 4;

    f32x4 acc[3][6] = {};

    G2_ISSUE(0, 0);

    const int NT = H1 / 64;   // 8
    for (int t = 0; t < NT; ++t) {
        __syncthreads();
        if (t + 1 < NT) G2_ISSUE((t + 1) & 1, (t + 1) * 64);
        const int cb = t & 1;
        #pragma unroll
        for (int kk = 0; kk < 2; ++kk) {
            half8 af[3], bf[6];
            #pragma unroll
            for (int i = 0; i < 3; ++i) {
                int row = wrow + i * 16 + fr;
                af[i] = *(const half8*)&As[cb][
                    (row * 64 + kk * 32 + fg * 8) ^ ((row & 7) << 3)];
            }
            #pragma unroll
            for (int j = 0; j < 6; ++j) {
                int row = wcol + j * 16 + fr;
                bf[j] = *(const half8*)&Bs[cb][
                    (row * 64 + kk * 32 + fg * 8) ^ ((row & 7) << 3)];
            }
            #pragma unroll
            for (int i = 0; i < 3; ++i)
                #pragma unroll
                for (int j = 0; j < 6; ++j)
                    acc[i][j] = __builtin_amdgcn_mfma_f32_16x16x32_f16(af[i], bf[j], acc[i][j], 0, 0, 0);
        }
    }

    #pragma unroll
    for (int i = 0; i < 3; ++i) {
        #pragma unroll
        for (int j = 0; j < 6; ++j) {
            int col = bn * 192 + wcol + j * 16 + fr;
            float bias = b2[col];
            #pragma unroll
            for (int r = 0; r < 4; ++r) {
                int row = bm * 96 + wrow + i * 16 + fg * 4 + r;
                out[(size_t)row * H2 + col] = acc[i][j][r] + bias;
            }
        }
    }
    #undef G2_ISSUE
}

extern "C" void kernel_launch(void* const* d_in, const int* in_sizes, int n_in,
                              void* d_out, int out_size, void* d_ws, size_t ws_size,
                              hipStream_t stream) {
    const float* concat_output  = (const float*)d_in[0];
    const int*   input_ids      = (const int*)d_in[1];
    const int*   topic_ids      = (const int*)d_in[2];
    const int*   tpw_att_mask   = (const int*)d_in[3];
    const int*   tpw_type_ids   = (const int*)d_in[4];
    const int*   attention_mask = (const int*)d_in[5];
    const int*   type_ids       = (const int*)d_in[6];
    const float* token_table    = (const float*)d_in[7];
    const float* W1             = (const float*)d_in[8];
    const float* b1             = (const float*)d_in[9];
    const float* W2             = (const float*)d_in[10];
    const float* b2             = (const float*)d_in[11];
    float* out = (float*)d_out;

    _Float16* w1t = (_Float16*)d_ws;            // [512][2048]   2.0 MB
    _Float16* w2t = w1t + (size_t)H1 * DD;      // [768][512]    0.75 MB
    _Float16* Hws = w2t + (size_t)H2 * H1;      // [12288][512]  12.6 MB
    _Float16* A16 = Hws + (size_t)MM * H1;      // [12288][2048] 50.3 MB

    transpose_f16_kernel<<<dim3(H1 / 32, DD / 32), 256, 0, stream>>>(W1, w1t, DD, H1);
    transpose_f16_kernel<<<dim3(H2 / 32, H1 / 32), 256, 0, stream>>>(W2, w2t, H1, H2);
    gather_kernel<<<MM, 256, 0, stream>>>(
        token_table, topic_ids, input_ids, concat_output,
        tpw_type_ids, type_ids, tpw_att_mask, attention_mask, A16, out);

    gemm1_kernel<<<(MM / 64) * (H1 / 64), 256, 0, stream>>>(A16, w1t, b1, Hws);
    gemm2_kernel<<<(MM / 96) * (H2 / 192), 256, 0, stream>>>(Hws, w2t, b2, out);
}